// Round 1
// baseline (12.457 us; speedup 1.0000x reference)
//
#include <hip/hip_runtime.h>
#include <math.h>

// Problem: B=64, L=100, D=16, N=1024. Output y[b,l,d] (f32, 102400 elems).
//
// Algebraic collapse (see analysis): dA is multiplied by 0 (h init), so
//   y[t,d] = x[t,d] * softplus(x[t]·W1[:,d] + b1[d]) * s(t)
//   s(t)   = v^T M v + v·uv + c,   v = x[t,:],
//   M = W2 W3^T (16x16), uv[i] = Σ_n W2[i,n]b3[n]+W3[i,n]b2[n], c = b2·b3.

#define DD 16
#define NN 1024

// ---------------- kernel 1: precompute M (256), uv (16), c (1) into ws ----
__global__ __launch_bounds__(256) void s6_precompute(
    const float* __restrict__ W2, const float* __restrict__ b2,
    const float* __restrict__ W3, const float* __restrict__ b3,
    float* __restrict__ ws)
{
    int wave = blockIdx.x * 4 + (threadIdx.x >> 6);
    int lane = threadIdx.x & 63;
    float acc = 0.f;
    if (wave < 256) {                       // M[i][j] = Σ_n W2[i,n]*W3[j,n]
        int i = wave >> 4, j = wave & 15;
        const float* r2 = W2 + i * NN;
        const float* r3 = W3 + j * NN;
        #pragma unroll
        for (int w = 0; w < 4; ++w) {
            int n0 = w * 256 + lane * 4;    // coalesced float4 per wave
            float4 a = *(const float4*)(r2 + n0);
            float4 b = *(const float4*)(r3 + n0);
            acc += a.x*b.x + a.y*b.y + a.z*b.z + a.w*b.w;
        }
    } else if (wave < 272) {                // uv[i]
        int i = wave - 256;
        const float* r2 = W2 + i * NN;
        const float* r3 = W3 + i * NN;
        #pragma unroll
        for (int w = 0; w < 4; ++w) {
            int n0 = w * 256 + lane * 4;
            float4 a2 = *(const float4*)(r2 + n0);
            float4 a3 = *(const float4*)(r3 + n0);
            float4 v2 = *(const float4*)(b2 + n0);
            float4 v3 = *(const float4*)(b3 + n0);
            acc += a2.x*v3.x + a2.y*v3.y + a2.z*v3.z + a2.w*v3.w;
            acc += a3.x*v2.x + a3.y*v2.y + a3.z*v2.z + a3.w*v2.w;
        }
    } else if (wave == 272) {               // c = b2·b3
        #pragma unroll
        for (int w = 0; w < 4; ++w) {
            int n0 = w * 256 + lane * 4;
            float4 v2 = *(const float4*)(b2 + n0);
            float4 v3 = *(const float4*)(b3 + n0);
            acc += v2.x*v3.x + v2.y*v3.y + v2.z*v3.z + v2.w*v3.w;
        }
    } else {
        return;
    }
    #pragma unroll
    for (int o = 32; o >= 1; o >>= 1) acc += __shfl_xor(acc, o, 64);
    if (lane == 0) ws[wave] = acc;          // ws[0..255]=M, [256..271]=uv, [272]=c
}

// ---------------- kernel 2: per-token fused output ------------------------
// 256 threads = 16 tokens x 16 lanes. Token T = blk*16 + (tid>>4), d = tid&15.
__global__ __launch_bounds__(256) void s6_fused(
    const float* __restrict__ x, const float* __restrict__ W1,
    const float* __restrict__ b1, const float* __restrict__ ws,
    float* __restrict__ out)
{
    __shared__ float xs[256];       // 16 tokens x 16 dims
    __shared__ float w1s[256];      // W1[k*16+d]
    __shared__ float b1s[DD];
    __shared__ float uvs[DD];
    __shared__ float ms[DD * 17];   // M padded to 17 -> row reads hit 16 banks

    const int tid  = threadIdx.x;
    const int base = blockIdx.x * 256;

    xs[tid]  = x[base + tid];                       // coalesced 1KB
    w1s[tid] = W1[tid];
    ms[(tid >> 4) * 17 + (tid & 15)] = ws[tid];
    if (tid < DD) { b1s[tid] = b1[tid]; uvs[tid] = ws[256 + tid]; }
    const float c = ws[272];                        // uniform -> scalar load
    __syncthreads();

    const int g = tid >> 4, d = tid & 15;

    float v[DD];
    #pragma unroll
    for (int k = 0; k < DD; ++k) v[k] = xs[g * DD + k];   // broadcast reads

    // delta_d = softplus(b1[d] + v · W1[:,d])
    float td = b1s[d];
    #pragma unroll
    for (int k = 0; k < DD; ++k) td = fmaf(v[k], w1s[k * DD + d], td);
    const float delta = fmaxf(td, 0.f) + log1pf(expf(-fabsf(td)));

    // p_d = v[d] * (M[d,:]·v + uv[d]);  s = Σ_d p_d + c  (16-lane reduce)
    float row = uvs[d];
    #pragma unroll
    for (int j = 0; j < DD; ++j) row = fmaf(ms[d * 17 + j], v[j], row);
    float p = v[d] * row;
    #pragma unroll
    for (int o = 1; o < 16; o <<= 1) p += __shfl_xor(p, o, 64);
    const float s = p + c;

    out[base + tid] = v[d] * delta * s;             // coalesced
}

extern "C" void kernel_launch(void* const* d_in, const int* in_sizes, int n_in,
                              void* d_out, int out_size, void* d_ws, size_t ws_size,
                              hipStream_t stream) {
    const float* x  = (const float*)d_in[0];
    const float* W1 = (const float*)d_in[1];
    const float* b1 = (const float*)d_in[2];
    const float* W2 = (const float*)d_in[3];
    const float* b2 = (const float*)d_in[4];
    const float* W3 = (const float*)d_in[5];
    const float* b3 = (const float*)d_in[6];
    // d_in[7] = A_log: dead in the reference (dA * 0.0), intentionally unused.
    float* out = (float*)d_out;
    float* ws  = (float*)d_ws;   // needs 273 floats

    // 273 waves of work -> 69 blocks x 4 waves
    s6_precompute<<<69, 256, 0, stream>>>(W2, b2, W3, b3, ws);
    // 6400 tokens / 16 per block = 400 blocks
    s6_fused<<<400, 256, 0, stream>>>(x, W1, b1, ws, out);
}